// Round 6
// baseline (4185.452 us; speedup 1.0000x reference)
//
#include <hip/hip_runtime.h>
#include <math.h>

// Problem constants (fixed by the reference)
constexpr int N_ = 50000;   // nodes
constexpr int E_ = 600000;  // edges per relation
constexpr int F_ = 256;     // feature dim
constexpr int H_ = 128;     // hidden dim
constexpr int Q_ = 64;      // query dim (== one wave)
constexpr int R_ = 2;       // relations
constexpr int L_ = 2;       // conv depth

#define MODE_STORE 0
#define MODE_TANH  1
#define MODE_ACC   2

// ---------------------------------------------------------------------------
// Tiled f32 GEMM, 64 rows x 128 cols per block, register-prefetch +
// LDS double-buffer (R5-verified). Only BT=true is instantiated now.
// ---------------------------------------------------------------------------
template <bool BT>
__global__ __launch_bounds__(256) void gemm_kernel(
    const float* __restrict__ A, int lda,
    const float* __restrict__ B, int ldb,
    float* __restrict__ C, int ldc,
    int M, int K,
    const float* __restrict__ rowscale, int mode)
{
    __shared__ __align__(16) float As[2][16][68];
    __shared__ __align__(16) float Bs[2][16][132];

    const int row0 = blockIdx.x * 64;
    const int col0 = blockIdx.y * 128;
    const int tid  = threadIdx.x;
    const int tm = tid >> 4;
    const int tn = tid & 15;

    const int am  = tid >> 2;
    const int ak4 = (tid & 3) * 4;
    const int bj  = tid >> 1;
    const int bk8 = (tid & 1) * 8;
    const int bk  = tid >> 5;
    const int bj4 = (tid & 31) * 4;

    auto loadA = [&](int kk) -> float4 {
        const int r = row0 + am;
        if (r < M) return *(const float4*)(A + (size_t)r * lda + kk + ak4);
        return make_float4(0.f, 0.f, 0.f, 0.f);
    };
    auto loadB = [&](int kk, float4& v0, float4& v1) {
        if (BT) {
            const float* bp = B + (size_t)(col0 + bj) * ldb + kk + bk8;
            v0 = *(const float4*)(bp);
            v1 = *(const float4*)(bp + 4);
        } else {
            v0 = *(const float4*)(B + (size_t)(kk + bk) * ldb + col0 + bj4);
            v1 = *(const float4*)(B + (size_t)(kk + bk + 8) * ldb + col0 + bj4);
        }
    };
    auto storeT = [&](int b, float4 va, float4 v0, float4 v1) {
        As[b][ak4 + 0][am] = va.x; As[b][ak4 + 1][am] = va.y;
        As[b][ak4 + 2][am] = va.z; As[b][ak4 + 3][am] = va.w;
        if (BT) {
            Bs[b][bk8 + 0][bj] = v0.x; Bs[b][bk8 + 1][bj] = v0.y;
            Bs[b][bk8 + 2][bj] = v0.z; Bs[b][bk8 + 3][bj] = v0.w;
            Bs[b][bk8 + 4][bj] = v1.x; Bs[b][bk8 + 5][bj] = v1.y;
            Bs[b][bk8 + 6][bj] = v1.z; Bs[b][bk8 + 7][bj] = v1.w;
        } else {
            Bs[b][bk + 0][bj4 + 0] = v0.x; Bs[b][bk + 0][bj4 + 1] = v0.y;
            Bs[b][bk + 0][bj4 + 2] = v0.z; Bs[b][bk + 0][bj4 + 3] = v0.w;
            Bs[b][bk + 8][bj4 + 0] = v1.x; Bs[b][bk + 8][bj4 + 1] = v1.y;
            Bs[b][bk + 8][bj4 + 2] = v1.z; Bs[b][bk + 8][bj4 + 3] = v1.w;
        }
    };

    float acc[4][8] = {};

    {
        float4 va = loadA(0), v0, v1;
        loadB(0, v0, v1);
        storeT(0, va, v0, v1);
    }
    __syncthreads();

    int cur = 0;
    for (int kk = 16; ; kk += 16) {
        const bool more = (kk < K);
        float4 na, n0, n1;
        if (more) { na = loadA(kk); loadB(kk, n0, n1); }

        #pragma unroll
        for (int k = 0; k < 16; k++) {
            const float4 av  = *(const float4*)&As[cur][k][tm * 4];
            const float4 bv0 = *(const float4*)&Bs[cur][k][tn * 8];
            const float4 bv1 = *(const float4*)&Bs[cur][k][tn * 8 + 4];
            const float a[4] = {av.x, av.y, av.z, av.w};
            const float b[8] = {bv0.x, bv0.y, bv0.z, bv0.w,
                                bv1.x, bv1.y, bv1.z, bv1.w};
            #pragma unroll
            for (int i = 0; i < 4; i++)
                #pragma unroll
                for (int j = 0; j < 8; j++)
                    acc[i][j] += a[i] * b[j];
        }
        if (!more) break;
        storeT(cur ^ 1, na, n0, n1);
        __syncthreads();
        cur ^= 1;
    }

    #pragma unroll
    for (int i = 0; i < 4; i++) {
        const int r = row0 + tm * 4 + i;
        if (r >= M) continue;
        const float rs = rowscale ? rowscale[r] : 1.0f;
        #pragma unroll
        for (int j = 0; j < 8; j++) {
            const int c = col0 + tn * 8 + j;
            float v = acc[i][j] * rs;
            if (mode == MODE_TANH) v = tanhf(v);
            float* p = C + (size_t)r * ldc + c;
            if (mode == MODE_ACC) *p += v;
            else                  *p = v;
        }
    }
}

// ---------------------------------------------------------------------------
// conv_dual: for relation r = blockIdx.y, computes BOTH
//   hs_r = g_r @ W_r          (128 cols, raw: si_in scale + bias applied later)
//   T_r  = g_r @ (W_r @ W1)   (64 cols, the attention-score pre-matvec)
// as one 64x192 tile from one A staging. Double-buffered like gemm_kernel.
// In-place hs_r == g_r is safe: a block's A-reads are exactly its own output
// rows, and all loads complete before the epilogue stores.
// (hs/T deliberately NOT __restrict__: in-place calls alias them with g.)
// ---------------------------------------------------------------------------
__global__ __launch_bounds__(256) void conv_dual(
    const float* g0, const float* g1,
    const float* __restrict__ Wlo,   // convW + lo*R*H*H
    const float* __restrict__ WWlo,  // ww1  + lo*R*H*Q
    float* hs0, float* hs1,
    float* T,                        // T0 = T, T1 = T + M*Q
    int M)
{
    __shared__ __align__(16) float As[2][16][68];
    __shared__ __align__(16) float Bs[2][16][200];

    const int r = blockIdx.y;
    const float* A  = r ? g1 : g0;
    const float* __restrict__ W  = Wlo  + (size_t)r * H_ * H_;
    const float* __restrict__ WW = WWlo + (size_t)r * H_ * Q_;
    float* hs = r ? hs1 : hs0;
    float* Tr = T + (size_t)r * M * Q_;

    const int row0 = blockIdx.x * 64;
    const int tid  = threadIdx.x;
    const int tm = tid >> 4;
    const int tn = tid & 15;

    const int am  = tid >> 2;
    const int ak4 = (tid & 3) * 4;

    // B mapping: f = tid + i*256 (i=0..2): k = f/48, col = (f%48)*4 (192 cols)
    int bk_[3], bc_[3];
    #pragma unroll
    for (int i = 0; i < 3; i++) {
        const int f = tid + i * 256;
        bk_[i] = f / 48;
        bc_[i] = (f % 48) * 4;
    }

    auto loadA = [&](int kk) -> float4 {
        const int rr = row0 + am;
        if (rr < M) return *(const float4*)(A + (size_t)rr * H_ + kk + ak4);
        return make_float4(0.f, 0.f, 0.f, 0.f);
    };
    auto loadB = [&](int kk, float4* v) {
        #pragma unroll
        for (int i = 0; i < 3; i++) {
            const int k = kk + bk_[i];
            const int c = bc_[i];
            v[i] = (c < H_) ? *(const float4*)(W  + (size_t)k * H_ + c)
                            : *(const float4*)(WW + (size_t)k * Q_ + (c - H_));
        }
    };
    auto storeT = [&](int b, float4 va, const float4* v) {
        As[b][ak4 + 0][am] = va.x; As[b][ak4 + 1][am] = va.y;
        As[b][ak4 + 2][am] = va.z; As[b][ak4 + 3][am] = va.w;
        #pragma unroll
        for (int i = 0; i < 3; i++) {
            Bs[b][bk_[i]][bc_[i] + 0] = v[i].x;
            Bs[b][bk_[i]][bc_[i] + 1] = v[i].y;
            Bs[b][bk_[i]][bc_[i] + 2] = v[i].z;
            Bs[b][bk_[i]][bc_[i] + 3] = v[i].w;
        }
    };

    float acc[4][12] = {};

    {
        float4 va = loadA(0), vb[3];
        loadB(0, vb);
        storeT(0, va, vb);
    }
    __syncthreads();

    int cur = 0;
    for (int kk = 16; ; kk += 16) {
        const bool more = (kk < H_);
        float4 na, nb[3];
        if (more) { na = loadA(kk); loadB(kk, nb); }

        #pragma unroll
        for (int k = 0; k < 16; k++) {
            const float4 av  = *(const float4*)&As[cur][k][tm * 4];
            const float4 bv0 = *(const float4*)&Bs[cur][k][tn * 12];
            const float4 bv1 = *(const float4*)&Bs[cur][k][tn * 12 + 4];
            const float4 bv2 = *(const float4*)&Bs[cur][k][tn * 12 + 8];
            const float a[4]  = {av.x, av.y, av.z, av.w};
            const float b[12] = {bv0.x, bv0.y, bv0.z, bv0.w,
                                 bv1.x, bv1.y, bv1.z, bv1.w,
                                 bv2.x, bv2.y, bv2.z, bv2.w};
            #pragma unroll
            for (int i = 0; i < 4; i++)
                #pragma unroll
                for (int j = 0; j < 12; j++)
                    acc[i][j] += a[i] * b[j];
        }
        if (!more) break;
        storeT(cur ^ 1, na, nb);
        __syncthreads();
        cur ^= 1;
    }

    #pragma unroll
    for (int i = 0; i < 4; i++) {
        const int rr = row0 + tm * 4 + i;
        if (rr >= M) continue;
        #pragma unroll
        for (int j = 0; j < 12; j++) {
            const int c = tn * 12 + j;
            const float v = acc[i][j];
            if (c < H_) hs[(size_t)rr * H_ + c] = v;
            else        Tr[(size_t)rr * Q_ + (c - H_)] = v;
        }
    }
}

// ---------------------------------------------------------------------------
// Once-per-launch weight prep:  ww1[c] = W_c @ W1_c  (128x64),
//   bbq[c] = bias_c @ W1_c + b1_c  (64),  c = lo*2 + r, lo = sign*L + l.
// ---------------------------------------------------------------------------
__global__ __launch_bounds__(256) void prep_ww1(
    const float* __restrict__ convW, const float* __restrict__ convB,
    const float* __restrict__ aW1, const float* __restrict__ aB1,
    float* __restrict__ ww1, float* __restrict__ bbq)
{
    const int c  = blockIdx.x;      // 0..7
    const int lo = c >> 1;
    const int r  = c & 1;
    const float* W  = convW + ((size_t)lo * R_ + r) * H_ * H_;
    const float* W1 = aW1 + (size_t)lo * H_ * Q_;
    const float* bs = convB + ((size_t)lo * R_ + r) * H_;
    const float* b1 = aB1 + (size_t)lo * Q_;
    float* o = ww1 + (size_t)c * H_ * Q_;

    for (int ofs = threadIdx.x; ofs < H_ * Q_; ofs += 256) {
        const int k = ofs >> 6, q = ofs & 63;
        float s = 0.f;
        for (int i = 0; i < H_; i++) s += W[k * H_ + i] * W1[i * Q_ + q];
        o[ofs] = s;
    }
    if (threadIdx.x < Q_) {
        const int q = threadIdx.x;
        float s = 0.f;
        for (int i = 0; i < H_; i++) s += bs[i] * W1[i * Q_ + q];
        bbq[c * Q_ + q] = s + b1[q];
    }
}

// ---------------------------------------------------------------------------
// Zero ints
// ---------------------------------------------------------------------------
__global__ __launch_bounds__(256) void zero_i(int* __restrict__ p, int n)
{
    int t = blockIdx.x * 256 + threadIdx.x;
    if (t < n) p[t] = 0;
}

// ---------------------------------------------------------------------------
// Degree counting: eb is the contiguous (R,2,E) int block for this sign.
// cnt layout: [which = r*2 + (0=src/out,1=dst/in)] x N
// ---------------------------------------------------------------------------
__global__ __launch_bounds__(256) void count_deg(const int* __restrict__ eb,
                                                 int* __restrict__ cnt, int total)
{
    int t = blockIdx.x * 256 + threadIdx.x;
    if (t >= total) return;
    int which = t / E_;
    atomicAdd(&cnt[which * N_ + eb[t]], 1);
}

// dscale[i] = rsqrt(max(cnt[i],1))
__global__ __launch_bounds__(256) void deg_finalize(const int* __restrict__ cnt,
                                                    float* __restrict__ dscale, int n)
{
    int t = blockIdx.x * 256 + threadIdx.x;
    if (t < n) {
        int v = cnt[t];
        dscale[t] = rsqrtf((float)(v < 1 ? 1 : v));
    }
}

// ---------------------------------------------------------------------------
// 3-phase parallel exclusive scan of in-degree counts -> CSR offsets+cursor.
// ---------------------------------------------------------------------------
constexpr int SCAN_NB = (N_ + 255) / 256;   // 196 blocks per relation

__global__ __launch_bounds__(256) void scan_p1(const int* __restrict__ cnt,
                                               int* __restrict__ bsums)
{
    const int r = blockIdx.y;
    const int* in = cnt + (size_t)(2 * r + 1) * N_;
    const int i = blockIdx.x * 256 + threadIdx.x;
    int v = (i < N_) ? in[i] : 0;
    #pragma unroll
    for (int off = 32; off > 0; off >>= 1) v += __shfl_xor(v, off);
    __shared__ int ws[4];
    if ((threadIdx.x & 63) == 0) ws[threadIdx.x >> 6] = v;
    __syncthreads();
    if (threadIdx.x == 0)
        bsums[r * SCAN_NB + blockIdx.x] = ws[0] + ws[1] + ws[2] + ws[3];
}

__global__ __launch_bounds__(256) void scan_p2(int* __restrict__ bsums)
{
    __shared__ int sh[256];
    const int r = blockIdx.x;
    const int t = threadIdx.x;
    int v = (t < SCAN_NB) ? bsums[r * SCAN_NB + t] : 0;
    sh[t] = v;
    __syncthreads();
    #pragma unroll
    for (int d = 1; d < 256; d <<= 1) {
        int u = (t >= d) ? sh[t - d] : 0;
        __syncthreads();
        sh[t] += u;
        __syncthreads();
    }
    if (t < SCAN_NB) bsums[r * SCAN_NB + t] = sh[t] - v;   // exclusive
}

__global__ __launch_bounds__(256) void scan_p3(const int* __restrict__ cnt,
                                               const int* __restrict__ bsums,
                                               int* __restrict__ offs,
                                               int* __restrict__ cursor)
{
    __shared__ int sh[256];
    const int r = blockIdx.y;
    const int* in = cnt + (size_t)(2 * r + 1) * N_;
    int* out = offs + (size_t)r * (N_ + 1);
    int* cur = cursor + (size_t)r * N_;
    const int i = blockIdx.x * 256 + threadIdx.x;
    const int t = threadIdx.x;
    int v = (i < N_) ? in[i] : 0;
    sh[t] = v;
    __syncthreads();
    #pragma unroll
    for (int d = 1; d < 256; d <<= 1) {
        int u = (t >= d) ? sh[t - d] : 0;
        __syncthreads();
        sh[t] += u;
        __syncthreads();
    }
    const int excl = sh[t] - v + bsums[r * SCAN_NB + blockIdx.x];
    if (i < N_) { out[i] = excl; cur[i] = excl; }
    if (i == 0) out[N_] = E_;
}

// csr[r*E + pos] = src, scl[r*E + pos] = degout_r^{-1/2}[src], bucketed by dst
__global__ __launch_bounds__(256) void csr_fill(const int* __restrict__ eb,
                                                int* __restrict__ cursor,
                                                int* __restrict__ csr,
                                                const float* __restrict__ dscale,
                                                float* __restrict__ scl, int total)
{
    int t = blockIdx.x * 256 + threadIdx.x;
    if (t >= total) return;
    int r = (t >= E_) ? 1 : 0;
    int e = t - r * E_;
    int s = eb[(r * 2 + 0) * E_ + e];
    int d = eb[(r * 2 + 1) * E_ + e];
    int pos = atomicAdd(&cursor[r * N_ + d], 1);
    csr[(size_t)r * E_ + pos] = s;
    scl[(size_t)r * E_ + pos] = dscale[(size_t)(2 * r) * N_ + s];
}

// ---------------------------------------------------------------------------
// gather2: g_r[dst] = sum over rel-r in-edges of h[src] * scl_r[edge].
// Both relations gather from the SAME 25.6 MB h array (halved working set
// vs gathering post-GEMM m0/m1). One wave per node, x4-unrolled loads,
// zero LDS -> occupancy capped only by waves (32/CU).
// ---------------------------------------------------------------------------
__global__ __launch_bounds__(256) void gather2(
    const float2* __restrict__ h,
    const int* __restrict__ offs0, const int* __restrict__ csr0, const float* __restrict__ scl0,
    const int* __restrict__ offs1, const int* __restrict__ csr1, const float* __restrict__ scl1,
    float2* __restrict__ g0, float2* __restrict__ g1, int n)
{
    const int lane = threadIdx.x & 63;
    int node = (blockIdx.x * 256 + threadIdx.x) >> 6;
    node = __builtin_amdgcn_readfirstlane(node);
    if (node >= n) return;

    float2 a0 = make_float2(0.f, 0.f), a1 = a0;
    {
        int k = offs0[node];
        const int e = offs0[node + 1];
        for (; k + 4 <= e; k += 4) {
            const int s0 = csr0[k + 0], s1 = csr0[k + 1];
            const int s2 = csr0[k + 2], s3 = csr0[k + 3];
            const float w0 = scl0[k + 0], w1 = scl0[k + 1];
            const float w2v = scl0[k + 2], w3 = scl0[k + 3];
            const float2 v0 = h[(size_t)s0 * 64 + lane];
            const float2 v1 = h[(size_t)s1 * 64 + lane];
            const float2 v2 = h[(size_t)s2 * 64 + lane];
            const float2 v3 = h[(size_t)s3 * 64 + lane];
            a0.x += v0.x * w0 + v1.x * w1 + v2.x * w2v + v3.x * w3;
            a0.y += v0.y * w0 + v1.y * w1 + v2.y * w2v + v3.y * w3;
        }
        for (; k < e; k++) {
            const int s = csr0[k];
            const float w = scl0[k];
            const float2 v = h[(size_t)s * 64 + lane];
            a0.x += v.x * w; a0.y += v.y * w;
        }
    }
    {
        int k = offs1[node];
        const int e = offs1[node + 1];
        for (; k + 4 <= e; k += 4) {
            const int s0 = csr1[k + 0], s1 = csr1[k + 1];
            const int s2 = csr1[k + 2], s3 = csr1[k + 3];
            const float w0 = scl1[k + 0], w1 = scl1[k + 1];
            const float w2v = scl1[k + 2], w3 = scl1[k + 3];
            const float2 v0 = h[(size_t)s0 * 64 + lane];
            const float2 v1 = h[(size_t)s1 * 64 + lane];
            const float2 v2 = h[(size_t)s2 * 64 + lane];
            const float2 v3 = h[(size_t)s3 * 64 + lane];
            a1.x += v0.x * w0 + v1.x * w1 + v2.x * w2v + v3.x * w3;
            a1.y += v0.y * w0 + v1.y * w1 + v2.y * w2v + v3.y * w3;
        }
        for (; k < e; k++) {
            const int s = csr1[k];
            const float w = scl1[k];
            const float2 v = h[(size_t)s * 64 + lane];
            a1.x += v.x * w; a1.y += v.y * w;
        }
    }
    g0[(size_t)node * 64 + lane] = a0;
    g1[(size_t)node * 64 + lane] = a1;
}

// ---------------------------------------------------------------------------
// attn_comb: light streaming attention combine. One wave per node.
//   t_rq = si_r[n] * T_r[n,q] + bbq_r[q]           (matvec pre-done in GEMM)
//   s_r  = sum_q tanh(t_rq) * w2[q]; softmax over r
//   out  = a0*(hs0*si0 + bias0) + a1*(hs1*si1 + bias1)
// outb may alias hs0p/hs1p (per-row read-before-write; rows are wave-private)
// -> these pointers are deliberately NOT __restrict__.
// ---------------------------------------------------------------------------
__global__ __launch_bounds__(256) void attn_comb(
    const float2* hs0p, const float2* hs1p,
    const float* __restrict__ T0, const float* __restrict__ T1,
    const float* __restrict__ si0, const float* __restrict__ si1,
    const float* __restrict__ bias0, const float* __restrict__ bias1,
    const float* __restrict__ bbq0, const float* __restrict__ bbq1,
    const float* __restrict__ w2,
    float2* outb, int n)
{
    __shared__ float bbqA[Q_], bbqB[Q_], w2s[Q_], bAs[H_], bBs[H_];
    const int tid = threadIdx.x;
    if (tid < Q_) { bbqA[tid] = bbq0[tid]; w2s[tid] = w2[tid]; }
    else if (tid < 2 * Q_) bbqB[tid - Q_] = bbq1[tid - Q_];
    if (tid < H_) bAs[tid] = bias0[tid];
    else bBs[tid - H_] = bias1[tid - H_];
    __syncthreads();

    const int lane = tid & 63;
    int node = (blockIdx.x * 256 + tid) >> 6;
    node = __builtin_amdgcn_readfirstlane(node);
    if (node >= n) return;

    const float t0v = T0[(size_t)node * Q_ + lane];
    const float t1v = T1[(size_t)node * Q_ + lane];
    const float si0n = si0[node], si1n = si1[node];
    const float2 h0v = hs0p[(size_t)node * 64 + lane];
    const float2 h1v = hs1p[(size_t)node * 64 + lane];

    float s0 = tanhf(si0n * t0v + bbqA[lane]) * w2s[lane];
    float s1 = tanhf(si1n * t1v + bbqB[lane]) * w2s[lane];
    #pragma unroll
    for (int off = 32; off > 0; off >>= 1) {
        s0 += __shfl_xor(s0, off);
        s1 += __shfl_xor(s1, off);
    }
    const float mx = fmaxf(s0, s1);
    const float e0v = expf(s0 - mx), e1v = expf(s1 - mx);
    const float a0 = e0v / (e0v + e1v), a1 = 1.0f - a0;

    float2 o;
    o.x = a0 * (h0v.x * si0n + bAs[2 * lane])     + a1 * (h1v.x * si1n + bBs[2 * lane]);
    o.y = a0 * (h0v.y * si0n + bAs[2 * lane + 1]) + a1 * (h1v.y * si1n + bBs[2 * lane + 1]);
    outb[(size_t)node * 64 + lane] = o;
}

// ---------------------------------------------------------------------------
// Orchestration
// ---------------------------------------------------------------------------
extern "C" void kernel_launch(void* const* d_in, const int* in_sizes, int n_in,
                              void* d_out, int out_size, void* d_ws, size_t ws_size,
                              hipStream_t stream)
{
    const float* x_attr = (const float*)d_in[0];
    const float* x_stru = (const float*)d_in[1];
    const int*   e_attr = (const int*)d_in[2];
    const int*   e_stru = (const int*)d_in[3];
    const float* Wf     = (const float*)d_in[4];
    const float* convW  = (const float*)d_in[5];
    const float* convB  = (const float*)d_in[6];
    const float* aW1    = (const float*)d_in[7];
    const float* aB1    = (const float*)d_in[8];
    const float* aW2    = (const float*)d_in[9];
    const float* Wc     = (const float*)d_in[10];
    float*       out    = (float*)d_out;
    float*       ws     = (float*)d_ws;

    const size_t NH = (size_t)N_ * H_;
    float* A  = ws;            // h0 -> hs0'(l1) -> hA
    float* Bb = ws + 1 * NH;   // hs1'(l1) -> h1
    float* C  = ws + 2 * NH;   // g0 -> hs0'(l0) -> g0' -> hs0' -> h2
    float* D  = ws + 3 * NH;   // g1 -> hs1'(l0) -> g1' -> hs1'
    float* Tb = ws + 4 * NH;   // T0 | T1  (each N x 64)
    float* dscale = ws + 5 * NH;                    // 4N
    int*   ibase  = (int*)(dscale + 4 * N_);
    int*   cnt    = ibase;                          // 4N
    int*   offs   = cnt + 4 * N_;                   // 2*(N+1), padded to %4
    constexpr int OFFS_PAD = 2 * (N_ + 1) + 2;      // 100004, 16B-aligned end
    int*   csr    = offs + OFFS_PAD;                // 2E
    int*   cursor = csr + 2 * E_;                   // 2N
    int*   bsums  = cursor + 2 * N_;                // 2*SCAN_NB (392)
    float* scl    = (float*)(bsums + 2 * SCAN_NB);  // 2E
    float* ww1    = scl + 2 * (size_t)E_;           // 8*H*Q (16B-aligned)
    float* bbq    = ww1 + 8 * H_ * Q_;              // 8*Q

    const int GX = (N_ + 63) / 64;                  // 782
    const dim3 GGEMM(GX, 1);
    const dim3 GCONV(GX, 2);
    const dim3 GSCAN(SCAN_NB, 2);
    const int PW_B = (N_ * 64) / 256;               // wave-per-node kernels: 12500

    // once: WW1 = W @ W1 and bbq = bias@W1 + b1 for all 8 (sign,l,r) combos
    prep_ww1<<<8, 256, 0, stream>>>(convW, convB, aW1, aB1, ww1, bbq);

    for (int run = 0; run < 4; run++) {
        const int sign = run >> 1;
        const float* x = (run & 1) ? x_stru : x_attr;
        const int* eb = ((run & 1) ? e_stru : e_attr) + (size_t)sign * (R_ * 2 * E_);
        float* y = out + (size_t)run * NH;
        const float* WcS = Wc + (size_t)sign * H_ * 3 * H_;

        // --- degrees + CSR build (once per run, reused by all layers) ---
        zero_i<<<(4 * N_ + 255) / 256, 256, 0, stream>>>(cnt, 4 * N_);
        count_deg<<<(4 * E_ + 255) / 256, 256, 0, stream>>>(eb, cnt, 4 * E_);
        deg_finalize<<<(4 * N_ + 255) / 256, 256, 0, stream>>>(cnt, dscale, 4 * N_);
        scan_p1<<<GSCAN, 256, 0, stream>>>(cnt, bsums);
        scan_p2<<<2, 256, 0, stream>>>(bsums);
        scan_p3<<<GSCAN, 256, 0, stream>>>(cnt, bsums, offs, cursor);
        csr_fill<<<(2 * E_ + 255) / 256, 256, 0, stream>>>(eb, cursor, csr,
                                                           dscale, scl, 2 * E_);

        // --- h0 = tanh(x @ Wf^T) -> A ---
        gemm_kernel<true><<<GGEMM, 256, 0, stream>>>(
            x, F_, Wf + (size_t)sign * H_ * F_, F_, A, H_, N_, F_, nullptr, MODE_TANH);

        // --- y = h0 @ Wc[:, 0:H]^T ---
        gemm_kernel<true><<<GGEMM, 256, 0, stream>>>(
            A, H_, WcS, 3 * H_, y, H_, N_, H_, nullptr, MODE_STORE);

        // --- g = gather(h0): shared by BOTH l=1 and l=0 layers ---
        gather2<<<PW_B, 256, 0, stream>>>(
            (const float2*)A, offs, csr, scl, offs + (N_ + 1), csr + E_, scl + E_,
            (float2*)C, (float2*)D, N_);

        auto convattn = [&](int l, float* hsA, float* hsB, float* dest) {
            const size_t lo = (size_t)(sign * L_ + l);
            conv_dual<<<GCONV, 256, 0, stream>>>(
                C, D,
                convW + lo * R_ * H_ * H_,
                ww1 + lo * R_ * H_ * Q_,
                hsA, hsB, Tb, N_);
            attn_comb<<<PW_B, 256, 0, stream>>>(
                (const float2*)hsA, (const float2*)hsB,
                Tb, Tb + (size_t)N_ * Q_,
                dscale + N_, dscale + 3 * N_,
                convB + (lo * R_ + 0) * H_, convB + (lo * R_ + 1) * H_,
                bbq + (lo * 2 + 0) * Q_, bbq + (lo * 2 + 1) * Q_,
                aW2 + lo * Q_,
                (float2*)dest, N_);
        };

        // --- h1 = het(h0, l=1): hs -> A (h0 dead), Bb; h1 -> Bb (row-alias ok)
        convattn(1, A, Bb, Bb);
        gemm_kernel<true><<<GGEMM, 256, 0, stream>>>(
            Bb, H_, WcS + H_, 3 * H_, y, H_, N_, H_, nullptr, MODE_ACC);

        // --- hA = het(h0, l=0): conv in-place over g (C,D dead after); hA -> A
        convattn(0, C, D, A);

        // --- g' = gather(hA) -> C,D ---
        gather2<<<PW_B, 256, 0, stream>>>(
            (const float2*)A, offs, csr, scl, offs + (N_ + 1), csr + E_, scl + E_,
            (float2*)C, (float2*)D, N_);

        // --- h2 = het(hA, l=1): conv in-place; h2 -> C (row-alias ok) ---
        convattn(1, C, D, C);
        gemm_kernel<true><<<GGEMM, 256, 0, stream>>>(
            C, H_, WcS + 2 * H_, 3 * H_, y, H_, N_, H_, nullptr, MODE_ACC);
    }
}